// Round 1
// baseline (247.025 us; speedup 1.0000x reference)
//
#include <hip/hip_runtime.h>

#define COLS 2048
#define TOPK 10
#define NEG_INF (-__builtin_inff())

// One wave (64 lanes) per row; block = 256 threads = 4 rows.
__global__ __launch_bounds__(256) void topk_mse_kernel(
    const float* __restrict__ input,
    const float* __restrict__ target,
    float* __restrict__ out,
    float inv_n)
{
    const int lane = threadIdx.x & 63;
    const int wv   = threadIdx.x >> 6;
    const int row  = (blockIdx.x << 2) + wv;

    const float* rp = input + (size_t)row * COLS + (lane << 2);

    // ---- load 32 elements per lane, coalesced float4 ----
    float e[32];
#pragma unroll
    for (int j = 0; j < 8; ++j) {
        float4 v = *reinterpret_cast<const float4*>(rp + j * 256);
        e[4*j+0] = v.x; e[4*j+1] = v.y; e[4*j+2] = v.z; e[4*j+3] = v.w;
    }

    // ---- phase 1: per-lane top-10 values (descending), branchless bubble ----
    float t[TOPK];
#pragma unroll
    for (int k = 0; k < TOPK; ++k) t[k] = NEG_INF;

#pragma unroll
    for (int i = 0; i < 32; ++i) {
        float v = e[i];
#pragma unroll
        for (int k = 0; k < TOPK; ++k) {
            float hi = fmaxf(t[k], v);
            v = fminf(t[k], v);
            t[k] = hi;
        }
    }

    // ---- phase 2: extract-max x9 across the wave, then the 10th max = v10 ----
#pragma unroll
    for (int it = 0; it < TOPK - 1; ++it) {
        float m = t[0];
#pragma unroll
        for (int off = 32; off >= 1; off >>= 1)
            m = fmaxf(m, __shfl_xor(m, off));
        unsigned long long b = __ballot(t[0] == m);
        bool pop = (lane == (__ffsll(b) - 1));   // exactly one popper on ties
#pragma unroll
        for (int k = 0; k < TOPK - 1; ++k) t[k] = pop ? t[k+1] : t[k];
        t[TOPK-1] = pop ? NEG_INF : t[TOPK-1];
    }
    float v10 = t[0];
#pragma unroll
    for (int off = 32; off >= 1; off >>= 1)
        v10 = fmaxf(v10, __shfl_xor(v10, off));

    // ---- phase 3: rescan registers vs threshold v10 ----
    float sum = 0.0f;
    int cnt = 0;
    unsigned eqm = 0;
#pragma unroll
    for (int i = 0; i < 32; ++i) {
        const int col = (lane << 2) + ((i >> 2) << 8) + (i & 3);
        const float w = (float)col * 0.1f + 1.0f;
        if (e[i] > v10) { sum += e[i] * w; cnt += 1; }
        else if (e[i] == v10) eqm |= (1u << i);
    }
#pragma unroll
    for (int off = 32; off >= 1; off >>= 1) {
        sum += __shfl_xor(sum, off);
        cnt += __shfl_xor(cnt, off);
    }

    // ties at the 10/11 boundary: take (10 - cnt) lowest-index equals,
    // matching jax.lax.top_k tie order. Usually exactly one iteration.
    int need = TOPK - cnt;
    while (need > 0) {
        int mycol = 0x7FFFFFFF;
        if (eqm) {
            const int s = __ffs(eqm) - 1;
            mycol = (lane << 2) + ((s >> 2) << 8) + (s & 3);
        }
        int wcol = mycol;
#pragma unroll
        for (int off = 32; off >= 1; off >>= 1)
            wcol = min(wcol, __shfl_xor(wcol, off));
        sum += v10 * ((float)wcol * 0.1f + 1.0f);   // replicated on all lanes
        if (mycol == wcol) eqm &= (eqm - 1);
        --need;
    }

    // ---- epilogue: squared error, block combine, one atomic per block ----
    __shared__ float partial[4];
    if (lane == 0) {
        const float d = target[row] - sum;
        partial[wv] = d * d * inv_n;
    }
    __syncthreads();
    if (threadIdx.x == 0)
        atomicAdd(out, partial[0] + partial[1] + partial[2] + partial[3]);
}

extern "C" void kernel_launch(void* const* d_in, const int* in_sizes, int n_in,
                              void* d_out, int out_size, void* d_ws, size_t ws_size,
                              hipStream_t stream) {
    const float* input  = (const float*)d_in[0];
    const float* target = (const float*)d_in[1];
    float* out = (float*)d_out;

    const int rows = in_sizes[1];           // 65536
    const float inv_n = 1.0f / (float)rows;

    hipMemsetAsync(out, 0, sizeof(float), stream);
    topk_mse_kernel<<<rows / 4, 256, 0, stream>>>(input, target, out, inv_n);
}

// Round 2
// 186.743 us; speedup vs baseline: 1.3228x; 1.3228x over previous
//
#include <hip/hip_runtime.h>

#define COLS 2048
#define TOPK 10

// One wave (64 lanes) per row; block = 256 threads = 4 rows.
// Writes per-row squared error to partials[row]; no atomics.
__global__ __launch_bounds__(256, 8) void topk_mse_main(
    const float* __restrict__ input,
    const float* __restrict__ target,
    float* __restrict__ partials)
{
    const int lane = threadIdx.x & 63;
    const int wv   = threadIdx.x >> 6;
    const int row  = (blockIdx.x << 2) + wv;

    const float* rp = input + (size_t)row * COLS + (lane << 2);
    const float tgt = target[row];          // broadcast, issued early

    // ---- load 32 elements per lane, coalesced float4 ----
    float e[32];
#pragma unroll
    for (int j = 0; j < 8; ++j) {
        float4 v = *reinterpret_cast<const float4*>(rp + j * 256);
        e[4*j+0] = v.x; e[4*j+1] = v.y; e[4*j+2] = v.z; e[4*j+3] = v.w;
    }

    // ---- per-lane max (tree, high ILP) ----
    float m0 = fmaxf(e[0], e[1]);
#pragma unroll
    for (int i = 2; i < 32; ++i) m0 = fmaxf(m0, e[i]);

    // ---- bitonic sort of the 64 lane-maxes, ascending across lanes ----
    float s = m0;
#pragma unroll
    for (int k = 2; k <= 64; k <<= 1) {
        const bool bk = (lane & k) != 0;
#pragma unroll
        for (int j = k >> 1; j > 0; j >>= 1) {
            float p = __shfl_xor(s, j);
            const bool take_min = (((lane & j) != 0) == bk);
            s = take_min ? fminf(s, p) : fmaxf(s, p);
        }
    }
    // 10th-largest lane-max = ascending position 54; lower bound for v10
    const float t0 = __shfl(s, 64 - TOPK);

    // ---- single rescan: count + weighted sum of candidates (e >= t0) ----
    float sum = 0.0f;
    int cnt = 0;
#pragma unroll
    for (int i = 0; i < 32; ++i) {
        const int col = (lane << 2) + ((i >> 2) << 8) + (i & 3);
        if (e[i] >= t0) {
            sum += e[i] * ((float)col * 0.1f + 1.0f);
            ++cnt;
        }
    }
#pragma unroll
    for (int off = 32; off >= 1; off >>= 1) {
        sum += __shfl_xor(sum, off);
        cnt += __shfl_xor(cnt, off);
    }

    // ---- drop the (cnt-10) smallest candidates; ties: remove highest col ----
    int excess = cnt - TOPK;            // always >= 0 by the bound proof
    unsigned removed = 0;
    while (excess > 0) {
        float lv = __builtin_inff();
        int   lc = -1;
#pragma unroll
        for (int i = 0; i < 32; ++i) {
            const int col = (lane << 2) + ((i >> 2) << 8) + (i & 3);
            const bool act = (e[i] >= t0) && !((removed >> i) & 1u);
            const bool better = act && ((e[i] < lv) || (e[i] == lv && col > lc));
            lv = better ? e[i] : lv;
            lc = better ? col  : lc;
        }
#pragma unroll
        for (int off = 32; off >= 1; off >>= 1) {
            const float pv = __shfl_xor(lv, off);
            const int   pc = __shfl_xor(lc, off);
            const bool take = (pv < lv) || (pv == lv && pc > lc);
            lv = take ? pv : lv;
            lc = take ? pc : lc;
        }
        sum -= lv * ((float)lc * 0.1f + 1.0f);      // wave-uniform
        if (((lc >> 2) & 63) == lane) {             // owner lane clears the slot
            const int i = ((lc >> 8) << 2) | (lc & 3);
            removed |= (1u << i);
        }
        --excess;
    }

    if (lane == 0) {
        const float d = tgt - sum;
        partials[row] = d * d;
    }
}

// Deterministic final reduction: 1 block, f64 accumulate.
__global__ __launch_bounds__(256) void topk_mse_reduce(
    const float* __restrict__ partials,
    float* __restrict__ out,
    int n, float inv_n)
{
    double s = 0.0;
    for (int i = threadIdx.x; i < n; i += 256) s += (double)partials[i];
#pragma unroll
    for (int off = 32; off >= 1; off >>= 1) s += __shfl_xor(s, off);
    __shared__ double ws[4];
    const int wv = threadIdx.x >> 6;
    if ((threadIdx.x & 63) == 0) ws[wv] = s;
    __syncthreads();
    if (threadIdx.x == 0)
        out[0] = (float)((ws[0] + ws[1] + ws[2] + ws[3]) * (double)inv_n);
}

extern "C" void kernel_launch(void* const* d_in, const int* in_sizes, int n_in,
                              void* d_out, int out_size, void* d_ws, size_t ws_size,
                              hipStream_t stream) {
    const float* input  = (const float*)d_in[0];
    const float* target = (const float*)d_in[1];
    float* out = (float*)d_out;
    float* partials = (float*)d_ws;         // rows * 4 bytes, well under ws_size

    const int rows = in_sizes[1];           // 65536
    const float inv_n = 1.0f / (float)rows;

    topk_mse_main<<<rows / 4, 256, 0, stream>>>(input, target, partials);
    topk_mse_reduce<<<1, 256, 0, stream>>>(partials, out, rows, inv_n);
}

// Round 4
// 95.057 us; speedup vs baseline: 2.5987x; 1.9645x over previous
//
#include <hip/hip_runtime.h>

#define COLS 2048
#define TOPK 10

typedef float f32x4 __attribute__((ext_vector_type(4)));

// One wave (64 lanes) per row; block = 256 threads = 4 rows.
// Each block writes ONE partial (sum of its 4 squared errors).
__global__ __launch_bounds__(256, 8) void topk_mse_main(
    const float* __restrict__ input,
    const float* __restrict__ target,
    float* __restrict__ partials)
{
    const int lane = threadIdx.x & 63;
    const int wv   = threadIdx.x >> 6;
    const int row  = (blockIdx.x << 2) + wv;

    const f32x4* rp4 = reinterpret_cast<const f32x4*>(input + (size_t)row * COLS) + lane;
    const float tgt = target[row];          // broadcast, issued early

    // ---- load 32 elements per lane, coalesced nontemporal float4 ----
    float e[32];
#pragma unroll
    for (int j = 0; j < 8; ++j) {
        f32x4 v = __builtin_nontemporal_load(rp4 + j * 64);
        e[4*j+0] = v.x; e[4*j+1] = v.y; e[4*j+2] = v.z; e[4*j+3] = v.w;
    }

    // ---- per-lane max: balanced tree (depth 5, v_max3-fusable) ----
    float m16[16];
#pragma unroll
    for (int i = 0; i < 16; ++i) m16[i] = fmaxf(e[2*i], e[2*i+1]);
#pragma unroll
    for (int i = 0; i < 8; ++i)  m16[i] = fmaxf(m16[2*i], m16[2*i+1]);
#pragma unroll
    for (int i = 0; i < 4; ++i)  m16[i] = fmaxf(m16[2*i], m16[2*i+1]);
    float m0 = fmaxf(fmaxf(m16[0], m16[1]), fmaxf(m16[2], m16[3]));

    // ---- bitonic sort of the 64 lane-maxes, ascending across lanes ----
    float s = m0;
#pragma unroll
    for (int k = 2; k <= 64; k <<= 1) {
        const bool bk = (lane & k) != 0;
#pragma unroll
        for (int j = k >> 1; j > 0; j >>= 1) {
            float p = __shfl_xor(s, j);
            const bool take_min = (((lane & j) != 0) == bk);
            s = take_min ? fminf(s, p) : fmaxf(s, p);
        }
    }
    // 10th-largest lane-max = ascending position 54; lower bound for row v10
    const float t0 = __shfl(s, 64 - TOPK);

    // ---- single rescan: wave-uniform count (SALU) + weighted sum ----
    // w(col) = 1 + 0.1*col = A(lane) + 0.1*off(slot),  A = 1 + 0.4*lane
    const float A = 1.0f + 0.4f * (float)lane;
    float s0 = 0.0f, s1 = 0.0f, s2 = 0.0f, s3 = 0.0f;
    int cnt = 0;
#pragma unroll
    for (int i = 0; i < 32; ++i) {
        const bool c = (e[i] >= t0);
        cnt += __popcll(__ballot(c));                 // SALU, wave-uniform
        const float m = c ? e[i] : 0.0f;
        const float offw = 0.1f * (float)(((i >> 2) << 8) + (i & 3));
        if ((i & 3) == 0)      { s0 = fmaf(m, A, fmaf(m, offw, s0)); }
        else if ((i & 3) == 1) { s1 = fmaf(m, A, fmaf(m, offw, s1)); }
        else if ((i & 3) == 2) { s2 = fmaf(m, A, fmaf(m, offw, s2)); }
        else                   { s3 = fmaf(m, A, fmaf(m, offw, s3)); }
    }
    float sum = (s0 + s1) + (s2 + s3);
#pragma unroll
    for (int off = 32; off >= 1; off >>= 1)
        sum += __shfl_xor(sum, off);

    // ---- drop the (cnt-10) smallest candidates; ties: remove highest col ----
    int excess = cnt - TOPK;            // >= 0 by the lane-max rank-10 bound
    unsigned removed = 0;
    while (excess > 0) {
        float lv = __builtin_inff();
        int   lc = -1;
#pragma unroll
        for (int i = 0; i < 32; ++i) {
            const int col = (lane << 2) + ((i >> 2) << 8) + (i & 3);
            const bool act = (e[i] >= t0) && !((removed >> i) & 1u);
            const bool better = act && ((e[i] < lv) || (e[i] == lv && col > lc));
            lv = better ? e[i] : lv;
            lc = better ? col  : lc;
        }
#pragma unroll
        for (int off = 32; off >= 1; off >>= 1) {
            const float pv = __shfl_xor(lv, off);
            const int   pc = __shfl_xor(lc, off);
            const bool take = (pv < lv) || (pv == lv && pc > lc);
            lv = take ? pv : lv;
            lc = take ? pc : lc;
        }
        sum -= lv * ((float)lc * 0.1f + 1.0f);      // wave-uniform
        if (((lc >> 2) & 63) == lane) {             // owner lane clears slot
            const int i = ((lc >> 8) << 2) | (lc & 3);
            removed |= (1u << i);
        }
        --excess;
    }

    // ---- block epilogue: 4 squared errors -> 1 partial ----
    __shared__ float ps[4];
    if (lane == 0) {
        const float d = tgt - sum;
        ps[wv] = d * d;
    }
    __syncthreads();
    if (threadIdx.x == 0)
        partials[blockIdx.x] = (ps[0] + ps[1]) + (ps[2] + ps[3]);
}

// Final reduction: 1 block, 256 threads, float4 loads, f64 accumulate.
__global__ __launch_bounds__(256) void topk_mse_reduce(
    const float* __restrict__ partials,
    float* __restrict__ out,
    int nb, float inv_n)
{
    const f32x4* p4 = reinterpret_cast<const f32x4*>(partials);
    const int nv = nb >> 2;                 // float4 count
    double s = 0.0;
    for (int i = threadIdx.x; i < nv; i += 256) {
        f32x4 v = p4[i];
        s += (double)v.x + (double)v.y + (double)v.z + (double)v.w;
    }
#pragma unroll
    for (int off = 32; off >= 1; off >>= 1) s += __shfl_xor(s, off);
    __shared__ double ws[4];
    const int wv = threadIdx.x >> 6;
    if ((threadIdx.x & 63) == 0) ws[wv] = s;
    __syncthreads();
    if (threadIdx.x == 0)
        out[0] = (float)(((ws[0] + ws[1]) + (ws[2] + ws[3])) * (double)inv_n);
}

extern "C" void kernel_launch(void* const* d_in, const int* in_sizes, int n_in,
                              void* d_out, int out_size, void* d_ws, size_t ws_size,
                              hipStream_t stream) {
    const float* input  = (const float*)d_in[0];
    const float* target = (const float*)d_in[1];
    float* out = (float*)d_out;
    float* partials = (float*)d_ws;         // nb * 4 bytes, well under ws_size

    const int rows = in_sizes[1];           // 65536
    const int nb = rows / 4;                // 16384 blocks
    const float inv_n = 1.0f / (float)rows;

    topk_mse_main<<<nb, 256, 0, stream>>>(input, target, partials);
    topk_mse_reduce<<<1, 256, 0, stream>>>(partials, out, nb, inv_n);
}